// Round 5
// baseline (89.827 us; speedup 1.0000x reference)
//
#include <hip/hip_runtime.h>
#include <hip/hip_fp16.h>

// Raymarcher: R=16384 rays, 64 steps, K=32 prims, template (32,4,16,16,16) f32.
// Round 15: attack VMEM address divergence. Pre-pass builds a corner-gathered
// cell table: for each base cell (k,iz,iy,ix) all 8 trilinear corners (4 fp16
// channels each) packed in ONE 64B cache line, ordered as the four x-pair
// chunks (z0y0, z0y1, z1y0, z1y1) so the factorized lerp is unchanged. March
// then does 1 addr + 4x16B loads from a single line per sample instead of 4
// scattered lines: ~4x fewer divergent line-requests through the L1 path,
// which r12-r14 showed to be the real bottleneck (ALU surgery was neutral).
// Costs 8 MiB workspace (ws >= 256 MB) and a ~2-3 us pre-pass.
// Keeps r14's loop: lane=(prim,parity), 4 substeps/iter, fast-path alpha,
// wave-uniform saturation break, DPP reduce, block=128.

namespace {

constexpr float kDT  = 1.0f / 64.0f;
constexpr int   kCells = 32 * 4096;   // (k, iz,iy,ix) padded 16^3 cells

struct H4 { __half2 lo, hi; };                                   // 4 fp16, 8 B
struct __attribute__((aligned(8))) H4x2 { __half2 l0, h0, l1, h1; }; // x-pair, 16 B
// One cell = 8 corners x 8 B = 64 B (line-aligned):
//   [c000 c001][c010 c011][c100 c101][c110 c111]  (chunks = p00,p01,p10,p11)

// ---- pre-pass: gather 8 corners per cell from (k,c,z,y,x) f32 template ----
__global__ __launch_bounds__(256) void build_cells(
    const float* __restrict__ tmpl, H4* __restrict__ wsC)
{
    const int idx = blockIdx.x * 256 + threadIdx.x;     // < 131072 cells
    const int k   = idx >> 12;
    const int rem = idx & 4095;
    const int iz  = rem >> 8;
    const int iy  = (rem >> 4) & 15;
    const int ix  = rem & 15;
    const float* base = tmpl + k * 16384;

    H4 cell[8];
    #pragma unroll
    for (int d = 0; d < 8; ++d) {
        const int z = min(iz + (d >> 2), 15);
        const int y = min(iy + ((d >> 1) & 1), 15);
        const int x = min(ix + (d & 1), 15);
        const float* s = base + z * 256 + y * 16 + x;
        cell[d].lo = __floats2half2_rn(s[0],    s[4096]);
        cell[d].hi = __floats2half2_rn(s[8192], s[12288]);
    }
    H4* dst = wsC + (size_t)idx * 8;
    *(H4x2*)(dst + 0) = *(H4x2*)&cell[0];
    *(H4x2*)(dst + 2) = *(H4x2*)&cell[2];
    *(H4x2*)(dst + 4) = *(H4x2*)&cell[4];
    *(H4x2*)(dst + 6) = *(H4x2*)&cell[6];
}

__device__ __forceinline__ __half2 lerp2(__half2 a, __half2 b, __half2 f) {
    return __hfma2(f, __hsub2(b, a), a);
}

template<int CTRL>
__device__ __forceinline__ float dpp_add(float v) {
    return v + __int_as_float(__builtin_amdgcn_update_dpp(
        0, __float_as_int(v), CTRL, 0xF, 0xF, true));
}

// Sum across each 32-lane half; result in every lane of that half.
__device__ __forceinline__ float half_sum32(float v) {
    v = dpp_add<0xB1>(v);    // quad_perm {1,0,3,2}  == lane^1
    v = dpp_add<0x4E>(v);    // quad_perm {2,3,0,1}  == lane^2
    v = dpp_add<0x141>(v);   // row_half_mirror      == lane^4 (groups uniform)
    v = dpp_add<0x140>(v);   // row_mirror           == lane^8 (groups uniform)
    v += __int_as_float(__builtin_amdgcn_ds_swizzle(__float_as_int(v), 0x401F)); // ^16
    return v;
}

__global__ __launch_bounds__(128) void raymarch15(
    const float* __restrict__ raypos,
    const float* __restrict__ raydir,
    const float* __restrict__ tminmax,
    const float* __restrict__ primpos,
    const float* __restrict__ primrot,
    const float* __restrict__ primscale,
    const H4* __restrict__ wsC,
    float* __restrict__ out,
    int R)
{
    const int lane   = threadIdx.x & 63;
    const int wid    = threadIdx.x >> 6;        // wave 0..1
    const int k      = lane & 31;               // prim owned by this lane
    const int parity = lane >> 5;               // substep parity (0 even, 1 odd)
    const int ray    = blockIdx.x * 2 + wid;    // one ray per wave

    const float rpx = raypos[ray * 3 + 0];
    const float rpy = raypos[ray * 3 + 1];
    const float rpz = raypos[ray * 3 + 2];
    const float rdx = raydir[ray * 3 + 0];
    const float rdy = raydir[ray * 3 + 1];
    const float rdz = raydir[ray * 3 + 2];
    const float tmin = tminmax[ray * 2 + 0];
    const float tmax = tminmax[ray * 2 + 1];

    // Fold prim k into affine y_i(t) = A_i + D_i*t (verified r1-r14 math).
    float A0, A1, A2, D0, D1, D2;
    {
        const float ox = rpx - primpos[k * 3 + 0];
        const float oy = rpy - primpos[k * 3 + 1];
        const float oz = rpz - primpos[k * 3 + 2];
        const float s0 = primscale[k * 3 + 0];
        const float s1 = primscale[k * 3 + 1];
        const float s2 = primscale[k * 3 + 2];
        const float* rk = primrot + k * 9;
        A0 = (rk[0] * ox + rk[1] * oy + rk[2] * oz) * s0;
        D0 = (rk[0] * rdx + rk[1] * rdy + rk[2] * rdz) * s0;
        A1 = (rk[3] * ox + rk[4] * oy + rk[5] * oz) * s1;
        D1 = (rk[3] * rdx + rk[4] * rdy + rk[5] * rdz) * s1;
        A2 = (rk[6] * ox + rk[7] * oy + rk[8] * oz) * s2;
        D2 = (rk[6] * rdx + rk[7] * rdy + rk[8] * rdz) * s2;
    }

    const H4* __restrict__ cbase = wsC + ((size_t)k << 15);  // k*4096 cells *8 H4

    float alpha = 0.f;                      // wave-uniform
    float r0 = 0.f, r1 = 0.f, r2 = 0.f;     // per-lane rgb partials

    // Per-lane coords for a given substep index (exact r10 arithmetic).
#define COORDS(SUB, IN, AD, FZ, FY, FX)                                  \
    {                                                                    \
        const float tl = fmaf((float)(SUB), kDT, tmin);                  \
        const float y0 = fmaf(D0, tl, A0);                               \
        const float y1 = fmaf(D1, tl, A1);                               \
        const float y2 = fmaf(D2, tl, A2);                               \
        IN = (tl < tmax) && fabsf(y0) <= 1.0f                            \
           && fabsf(y1) <= 1.0f && fabsf(y2) <= 1.0f;                    \
        const float gz = fmaf(y0, 7.5f, 7.5f);                           \
        const float gy = fmaf(y1, 7.5f, 7.5f);                           \
        const float gx = fmaf(y2, 7.5f, 7.5f);                           \
        const int iz = min((int)gz, 14);                                 \
        const int iy = min((int)gy, 14);                                 \
        const int ix = min((int)gx, 14);                                 \
        FZ = fminf(gz - (float)iz, 1.0f);                                \
        FY = fminf(gy - (float)iy, 1.0f);                                \
        FX = fminf(gx - (float)ix, 1.0f);                                \
        AD = iz * 256 + iy * 16 + ix;                                    \
    }

    // Trilinear eval: ONE 64B cell (4x16B same-line loads) + factorized lerp.
#define EVAL(IN, AD, FZ, FY, FX, S0, S1, S2, S3)                         \
    {                                                                    \
        S0 = 0.f; S1 = 0.f; S2 = 0.f; S3 = 0.f;                         \
        if (IN) {                                                        \
            const H4x2* cp = (const H4x2*)(cbase + ((size_t)(AD) * 8));  \
            const H4x2 p00 = cp[0];                                      \
            const H4x2 p01 = cp[1];                                      \
            const H4x2 p10 = cp[2];                                      \
            const H4x2 p11 = cp[3];                                      \
            const __half2 hz = __float2half2_rn(FZ);                     \
            const __half2 hy = __float2half2_rn(FY);                     \
            const __half2 hx = __float2half2_rn(FX);                     \
            const __half2 q0l0 = lerp2(p00.l0, p10.l0, hz);              \
            const __half2 q0h0 = lerp2(p00.h0, p10.h0, hz);              \
            const __half2 q0l1 = lerp2(p00.l1, p10.l1, hz);              \
            const __half2 q0h1 = lerp2(p00.h1, p10.h1, hz);              \
            const __half2 q1l0 = lerp2(p01.l0, p11.l0, hz);              \
            const __half2 q1h0 = lerp2(p01.h0, p11.h0, hz);              \
            const __half2 q1l1 = lerp2(p01.l1, p11.l1, hz);              \
            const __half2 q1h1 = lerp2(p01.h1, p11.h1, hz);              \
            const __half2 ul0 = lerp2(q0l0, q1l0, hy);                   \
            const __half2 uh0 = lerp2(q0h0, q1h0, hy);                   \
            const __half2 ul1 = lerp2(q0l1, q1l1, hy);                   \
            const __half2 uh1 = lerp2(q0h1, q1h1, hy);                   \
            const __half2 vl = lerp2(ul0, ul1, hx);                      \
            const __half2 vh = lerp2(uh0, uh1, hx);                      \
            const float2 fLo = __half22float2(vl);                       \
            const float2 fHi = __half22float2(vh);                       \
            S0 = fLo.x; S1 = fLo.y; S2 = fHi.x; S3 = fHi.y;              \
        }                                                                \
    }

    for (int j = 0; j < 16; ++j) {
        // quad j covers substeps 4j .. 4j+3; this lane evals 4j+parity
        // (slot a) and 4j+2+parity (slot b).
        bool  inA, inB;
        int   adA, adB;
        float fzA, fyA, fxA, fzB, fyB, fxB;
        COORDS(4 * j + parity,     inA, adA, fzA, fyA, fxA);
        COORDS(4 * j + 2 + parity, inB, adB, fzB, fyB, fxB);

        if (__ballot(inA || inB)) {
            float s0a, s1a, s2a, s3a, s0b, s1b, s2b, s3b;
            EVAL(inA, adA, fzA, fyA, fxA, s0a, s1a, s2a, s3a);
            EVAL(inB, adB, fzB, fyB, fxB, s0b, s1b, s2b, s3b);

            // half-local substep totals (each half holds one parity).
            const float ta = half_sum32(s3a);
            const float tb = half_sum32(s3b);
            const float sum2 = ta + tb;
            const float tot4 = sum2 + __shfl_xor(sum2, 32);  // all 4 substeps
            const float anew = fmaf(tot4, kDT, alpha);

            float ca, cb;
            if (anew < 1.0f) {
                // fast path: clamp inactive => contrib == inc, half-local.
                ca = ta * kDT;
                cb = tb * kDT;
                alpha = anew;
            } else {
                // slow path (at most once per ray): exact 4-term min chain.
                const float oa = __shfl_xor(ta, 32);
                const float ob = __shfl_xor(tb, 32);
                const float te0 = parity ? oa : ta;
                const float to0 = parity ? ta : oa;
                const float te1 = parity ? ob : tb;
                const float to1 = parity ? tb : ob;
                const float a1 = fminf(fmaf(te0, kDT, alpha), 1.0f);
                const float c0 = a1 - alpha;
                const float a2 = fminf(fmaf(to0, kDT, a1), 1.0f);
                const float c1 = a2 - a1;
                const float a3 = fminf(fmaf(te1, kDT, a2), 1.0f);
                const float c2 = a3 - a2;
                const float a4 = fminf(fmaf(to1, kDT, a3), 1.0f);
                const float c3 = a4 - a3;
                alpha = a4;
                ca = parity ? c1 : c0;
                cb = parity ? c3 : c2;
            }

            r0 = fmaf(s0a, ca, fmaf(s0b, cb, r0));
            r1 = fmaf(s1a, ca, fmaf(s1b, cb, r1));
            r2 = fmaf(s2a, ca, fmaf(s2b, cb, r2));
        }

        const float tn = fmaf((float)(4 * j + 4), kDT, tmin);
        if (tn >= tmax || alpha >= 1.0f) break;   // wave-uniform
    }

#undef COORDS
#undef EVAL

    // full-wave rgb reduce (both parity halves contributed)
    r0 = half_sum32(r0); r0 += __shfl_xor(r0, 32);
    r1 = half_sum32(r1); r1 += __shfl_xor(r1, 32);
    r2 = half_sum32(r2); r2 += __shfl_xor(r2, 32);

    if (lane == 0) {
        out[0 * R + ray] = r0;
        out[1 * R + ray] = r1;
        out[2 * R + ray] = r2;
        out[3 * R + ray] = alpha;
        out[4 * R + ray] = r0;
        out[5 * R + ray] = r1;
        out[6 * R + ray] = r2;
        out[7 * R + ray] = alpha;
    }
}

// ---- fallback (r6-style, original f32 template) for tiny ws ----
__global__ __launch_bounds__(256) void raymarch_fb(
    const float* __restrict__ raypos, const float* __restrict__ raydir,
    const float* __restrict__ tminmax, const float* __restrict__ primpos,
    const float* __restrict__ primrot, const float* __restrict__ primscale,
    const float* __restrict__ tmpl, float* __restrict__ out, int R)
{
    const int lane = threadIdx.x & 63;
    const int wid  = threadIdx.x >> 6;
    const int k    = lane & 31;
    const int half = lane >> 5;
    const int ray  = blockIdx.x * 8 + wid * 2 + half;

    const float rpx = raypos[ray*3+0], rpy = raypos[ray*3+1], rpz = raypos[ray*3+2];
    const float rdx = raydir[ray*3+0], rdy = raydir[ray*3+1], rdz = raydir[ray*3+2];
    const float tmin = tminmax[ray*2+0], tmax = tminmax[ray*2+1];

    float A0,A1,A2,D0,D1,D2;
    {
        const float ox = rpx - primpos[k*3+0], oy = rpy - primpos[k*3+1], oz = rpz - primpos[k*3+2];
        const float s0 = primscale[k*3+0], s1 = primscale[k*3+1], s2 = primscale[k*3+2];
        const float* rk = primrot + k*9;
        A0 = (rk[0]*ox+rk[1]*oy+rk[2]*oz)*s0; D0 = (rk[0]*rdx+rk[1]*rdy+rk[2]*rdz)*s0;
        A1 = (rk[3]*ox+rk[4]*oy+rk[5]*oz)*s1; D1 = (rk[3]*rdx+rk[4]*rdy+rk[5]*rdz)*s1;
        A2 = (rk[6]*ox+rk[7]*oy+rk[8]*oz)*s2; D2 = (rk[6]*rdx+rk[7]*rdy+rk[8]*rdz)*s2;
    }
    float alpha = 0.f, r0 = 0.f, r1 = 0.f, r2 = 0.f;
    for (int i = 0; i < 64; ++i) {
        const float t = fmaf((float)i, kDT, tmin);
        const bool live = (t < tmax) && (alpha < 1.0f);
        if (__ballot(live) == 0ull) break;
        const float y0 = fmaf(D0,t,A0), y1 = fmaf(D1,t,A1), y2 = fmaf(D2,t,A2);
        const bool inside = live && fabsf(y0)<=1.f && fabsf(y1)<=1.f && fabsf(y2)<=1.f;
        if (__ballot(inside) == 0ull) continue;
        float s0=0.f,s1=0.f,s2=0.f,s3=0.f;
        if (inside) {
            const float gz=(y0+1.f)*7.5f, gy=(y1+1.f)*7.5f, gx=(y2+1.f)*7.5f;
            const int iz=(int)fminf(floorf(gz),14.f), iy=(int)fminf(floorf(gy),14.f), ix=(int)fminf(floorf(gx),14.f);
            const float fz=fminf(gz-(float)iz,1.f), fy=fminf(gy-(float)iy,1.f), fx=fminf(gx-(float)ix,1.f);
            const float oz_=1.f-fz, oy_=1.f-fy, ox_=1.f-fx;
            const float w000=oz_*oy_*ox_, w001=oz_*oy_*fx, w010=oz_*fy*ox_, w011=oz_*fy*fx;
            const float w100=fz*oy_*ox_, w101=fz*oy_*fx, w110=fz*fy*ox_, w111=fz*fy*fx;
            const float* tp = tmpl + k*16384 + iz*256 + iy*16 + ix;
            float acc[4];
            #pragma unroll
            for (int c = 0; c < 4; ++c) {
                const float* tc = tp + c*4096;
                acc[c] = w000*tc[0]+w001*tc[1]+w010*tc[16]+w011*tc[17]
                       + w100*tc[256]+w101*tc[257]+w110*tc[272]+w111*tc[273];
            }
            s0=acc[0]; s1=acc[1]; s2=acc[2]; s3=acc[3];
        }
        float tot3 = s3;
        #pragma unroll
        for (int m = 1; m < 32; m <<= 1) tot3 += __shfl_xor(tot3, m);
        const float na = fminf(fmaf(tot3, kDT, alpha), 1.0f);
        const float contrib = na - alpha;
        alpha = na;
        r0 = fmaf(s0, contrib, r0); r1 = fmaf(s1, contrib, r1); r2 = fmaf(s2, contrib, r2);
    }
    #pragma unroll
    for (int m = 1; m < 32; m <<= 1) {
        r0 += __shfl_xor(r0, m); r1 += __shfl_xor(r1, m); r2 += __shfl_xor(r2, m);
    }
    if (k == 0) {
        out[0*R+ray]=r0; out[1*R+ray]=r1; out[2*R+ray]=r2; out[3*R+ray]=alpha;
        out[4*R+ray]=r0; out[5*R+ray]=r1; out[6*R+ray]=r2; out[7*R+ray]=alpha;
    }
}

} // namespace

extern "C" void kernel_launch(void* const* d_in, const int* in_sizes, int n_in,
                              void* d_out, int out_size, void* d_ws, size_t ws_size,
                              hipStream_t stream) {
    const float* raypos    = (const float*)d_in[0];
    const float* raydir    = (const float*)d_in[1];
    const float* tminmax   = (const float*)d_in[2];
    const float* primpos   = (const float*)d_in[3];
    const float* primrot   = (const float*)d_in[4];
    const float* primscale = (const float*)d_in[5];
    const float* tmpl      = (const float*)d_in[6];
    float* out = (float*)d_out;

    const int R = in_sizes[0] / 3;   // 16384
    const size_t needC = (size_t)kCells * 64;   // 8 MiB cell table

    if (ws_size >= needC) {
        H4* wsC = (H4*)d_ws;
        build_cells<<<dim3(kCells / 256), dim3(256), 0, stream>>>(tmpl, wsC);
        raymarch15<<<dim3(R / 2), dim3(128), 0, stream>>>(
            raypos, raydir, tminmax, primpos, primrot, primscale, wsC, out, R);
    } else {
        raymarch_fb<<<dim3(R / 8), dim3(256), 0, stream>>>(
            raypos, raydir, tminmax, primpos, primrot, primscale, tmpl, out, R);
    }
}